// Round 8
// baseline (2363.830 us; speedup 1.0000x reference)
//
#include <hip/hip_runtime.h>

typedef __bf16  bf16x8 __attribute__((ext_vector_type(8)));
typedef float   f32x4  __attribute__((ext_vector_type(4)));
typedef unsigned int uint32x2 __attribute__((ext_vector_type(2)));

#define MFMA16(a,b,c) __builtin_amdgcn_mfma_f32_16x16x32_bf16((a),(b),(c),0,0,0)

template<int V> struct ic_t { static constexpr int value = V; };

// bf16 weight arena layout in d_ws (elements)
enum : int {
    OFF_W0 = 0,                      // [256][64]
    OFF_W1 = OFF_W0 + 256 * 64,      // [256][256]
    OFF_W2 = OFF_W1 + 256 * 256,
    OFF_W3 = OFF_W2 + 256 * 256,
    OFF_W4 = OFF_W3 + 256 * 256,     // [256][320]
    OFF_W5 = OFF_W4 + 256 * 320,
    OFF_W6 = OFF_W5 + 256 * 256,
    OFF_W7 = OFF_W6 + 256 * 256,
    OFF_WF = OFF_W7 + 256 * 256,     // [256][256]
    OFF_WD = OFF_WF + 256 * 256,     // [128][288]
    W_TOTAL = OFF_WD + 128 * 288
};

__device__ __forceinline__ unsigned short f2bf(float f) {
    unsigned int u = __float_as_uint(f);
    u += 0x7FFFu + ((u >> 16) & 1u);
    return (unsigned short)(u >> 16);
}

// Soft barrier: LDS ops visible + rendezvous, but global loads stay in flight.
__device__ __forceinline__ void soft_barrier() {
    asm volatile("s_waitcnt lgkmcnt(0)" ::: "memory");
    __builtin_amdgcn_s_barrier();
}

__device__ __forceinline__ void prep_one(const float* __restrict__ src,
                                         unsigned short* __restrict__ dst,
                                         int fout, int Kp, int n1, int n2, int n3,
                                         int idx) {
    int n = idx / Kp;
    int k = idx - n * Kp;
    float v = 0.f;
    if (k < n1)                 v = src[k * fout + n];
    else if (k >= n2 && k < n3) v = src[(k - (n2 - n1)) * fout + n];
    dst[n * Kp + k] = f2bf(v);
}

__global__ void prep_kernel(const float* w0, const float* w1, const float* w2,
                            const float* w3, const float* w4, const float* w5,
                            const float* w6, const float* w7, const float* wf,
                            const float* wd, unsigned short* dst) {
    int i = blockIdx.x * 256 + threadIdx.x;
    if (i < 256 * 64)  { prep_one(w0, dst + OFF_W0, 256,  64,  63,  64,  64, i); return; }
    i -= 256 * 64;
    if (i < 256 * 256) { prep_one(w1, dst + OFF_W1, 256, 256, 256, 256, 256, i); return; }
    i -= 256 * 256;
    if (i < 256 * 256) { prep_one(w2, dst + OFF_W2, 256, 256, 256, 256, 256, i); return; }
    i -= 256 * 256;
    if (i < 256 * 256) { prep_one(w3, dst + OFF_W3, 256, 256, 256, 256, 256, i); return; }
    i -= 256 * 256;
    if (i < 256 * 320) { prep_one(w4, dst + OFF_W4, 256, 320,  63,  64, 320, i); return; }
    i -= 256 * 320;
    if (i < 256 * 256) { prep_one(w5, dst + OFF_W5, 256, 256, 256, 256, 256, i); return; }
    i -= 256 * 256;
    if (i < 256 * 256) { prep_one(w6, dst + OFF_W6, 256, 256, 256, 256, 256, i); return; }
    i -= 256 * 256;
    if (i < 256 * 256) { prep_one(w7, dst + OFF_W7, 256, 256, 256, 256, 256, i); return; }
    i -= 256 * 256;
    if (i < 256 * 256) { prep_one(wf, dst + OFF_WF, 256, 256, 256, 256, 256, i); return; }
    i -= 256 * 256;
    if (i < 128 * 288) { prep_one(wd, dst + OFF_WD, 128, 288, 286, 288, 288, i); return; }
}

struct Params {
    const float* x;
    const unsigned short* Wt;
    const float* b[8];
    const float* bfv;
    const float* bdv;
    const float* wsv;
    const float* bsv;
    const float* wrv;
    const float* brv;
    float* out;
};

// 64 rows/block, 4 waves (256 thr), N-split 64 cols/wave (NT=4).
// SINGLE 32 KB Hs, in-place layers (pre-epilogue barrier); x read directly
// from global for L0/L4/dir (no staging LDS). Target: 4 blocks/CU = 16
// waves/CU. Swapped MFMA (D=[neuron][batch]); depth-2 cross-layer B prefetch.
__global__ __launch_bounds__(256, 4) void nerf_kernel(Params P) {
    __shared__ char Hs[32768];   // [64][256] bf16, swz ^((row&7)<<4)

    const int t    = threadIdx.x;
    const int lane = t & 63;
    const int wave = t >> 6;          // 0..3
    const int lr   = lane & 15;
    const int lk   = lane >> 4;
    const int blockRow = blockIdx.x << 6;

    // ---- B pipeline (persistent across layers): bp0/bp1 = kt, kt+1 frags
    bf16x8 bp0[4], bp1[4];
    {   // preload layer-0 kt0/kt1
        const unsigned short* Wb0 = P.Wt + OFF_W0 + (size_t)((wave << 6) + lr) * 64 + (lk << 3);
#pragma unroll
        for (int nt = 0; nt < 4; ++nt) {
            bp0[nt] = *(const bf16x8*)(Wb0 + (size_t)(nt << 4) * 64);
            bp1[nt] = *(const bf16x8*)(Wb0 + (size_t)(nt << 4) * 64 + 32);
        }
    }

    // activation B-frag from GLOBAL x: batch row = blockRow+mt*16+lr,
    // k-elem j -> x col c0 + lk*8 + j, zero for c >= lim
    auto ldXg = [&](int mt, int c0, int lim) -> bf16x8 {
        const float* xr = P.x + (size_t)(blockRow + (mt << 4) + lr) * 93;
        bf16x8 r;
#pragma unroll
        for (int j = 0; j < 8; ++j) {
            int c = c0 + (lk << 3) + j;
            r[j] = (c < lim) ? (__bf16)xr[c] : (__bf16)0.f;
        }
        return r;
    };
    // activation B-frag from Hs: row = mt*16+lr, 16B contiguous k
    auto ldH = [&](int mt, int kt) -> bf16x8 {
        int row = (mt << 4) + lr;
        int off = (row * 512 + (kt << 6) + (lk << 4)) ^ ((row & 7) << 4);
        return *(const bf16x8*)(Hs + off);
    };

    // GEMM layer. KT=K/32, NT=N-tiles/wave, NTn = next layer's NT (0=none).
    // In-place: K-loop reads Hs -> soft barrier -> epilogue writes Hs.
    // Entry: bp0/bp1 = this layer's kt0/kt1. Exit: next layer's kt0/kt1.
    auto gemm = [&](auto KTt, auto NTt, auto NTnt, auto&& getA,
                    const unsigned short* W, int Kp, const float* bias, bool dorelu,
                    const unsigned short* Wn, int Kpn, int cbn) {
        constexpr int KT  = decltype(KTt)::value;
        constexpr int NT  = decltype(NTt)::value;
        constexpr int NTn = decltype(NTnt)::value;
        const int colbase = wave * (NT << 4);
        const unsigned short* Wb = W + (size_t)(colbase + lr) * Kp + (lk << 3);
        const unsigned short* Wbn = (NTn > 0) ? Wn + (size_t)(cbn + lr) * Kpn + (lk << 3) : nullptr;

        // bias folded into acc init (neuron = colbase + nt*16 + lk*4 + e)
        f32x4 acc[4][NT];
        {
            f32x4 bfr[NT];
#pragma unroll
            for (int nt = 0; nt < NT; ++nt)
                bfr[nt] = *(const f32x4*)(bias + colbase + (nt << 4) + (lk << 2));
#pragma unroll
            for (int mt = 0; mt < 4; ++mt)
#pragma unroll
                for (int nt = 0; nt < NT; ++nt) acc[mt][nt] = bfr[nt];
        }

        bf16x8 aC[4], aN[4];
#pragma unroll
        for (int mt = 0; mt < 4; ++mt) { aC[mt] = getA(mt, 0); aN[mt] = aC[mt]; }

#pragma unroll
        for (int kt = 0; kt < KT; ++kt) {
            // depth-2 B prefetch (wraps into next layer's kt0/kt1)
            bf16x8 bp2[NT];
            if (kt + 2 < KT) {
#pragma unroll
                for (int nt = 0; nt < NT; ++nt)
                    bp2[nt] = *(const bf16x8*)(Wb + (size_t)(nt << 4) * Kp + ((kt + 2) << 5));
            } else if (NTn > 0) {
#pragma unroll
                for (int nt = 0; nt < (NTn > 0 ? NTn : 1); ++nt)
                    bp2[nt] = *(const bf16x8*)(Wbn + (size_t)(nt << 4) * Kpn + ((kt + 2 - KT) << 5));
            } else {
#pragma unroll
                for (int nt = 0; nt < NT; ++nt) bp2[nt] = bp1[nt];
            }
            // A prefetch distance 1
            if (kt + 1 < KT) {
#pragma unroll
                for (int mt = 0; mt < 4; ++mt) aN[mt] = getA(mt, kt + 1);
            }
            __builtin_amdgcn_s_setprio(1);
#pragma unroll
            for (int nt = 0; nt < NT; ++nt) {
#pragma unroll
                for (int mt = 0; mt < 4; ++mt)
                    acc[mt][nt] = MFMA16(bp0[nt], aC[mt], acc[mt][nt]);  // D=[neuron][batch]
            }
            __builtin_amdgcn_s_setprio(0);
#pragma unroll
            for (int nt = 0; nt < 4; ++nt) { bp0[nt] = bp1[nt]; }
#pragma unroll
            for (int nt = 0; nt < NT; ++nt) { bp1[nt] = bp2[nt]; }
#pragma unroll
            for (int mt = 0; mt < 4; ++mt) aC[mt] = aN[mt];
        }

        // all waves done reading Hs before in-place overwrite
        soft_barrier();

        // epilogue: relu, pack 2x bf16 via cvt_pk, one b64 LDS write per tile
#pragma unroll
        for (int nt = 0; nt < NT; ++nt) {
#pragma unroll
            for (int mt = 0; mt < 4; ++mt) {
                f32x4 v = acc[mt][nt];
                if (dorelu) {
#pragma unroll
                    for (int e = 0; e < 4; ++e) v[e] = fmaxf(v[e], 0.f);
                }
                unsigned int lo, hi;
                asm("v_cvt_pk_bf16_f32 %0, %1, %2" : "=v"(lo) : "v"(v[0]), "v"(v[1]));
                asm("v_cvt_pk_bf16_f32 %0, %1, %2" : "=v"(hi) : "v"(v[2]), "v"(v[3]));
                int batch = (mt << 4) + lr;
                int off = (batch * 512 + ((colbase + (nt << 4) + (lk << 2)) << 1)) ^ ((batch & 7) << 4);
                uint32x2 w2 = {lo, hi};
                *(uint32x2*)(Hs + off) = w2;
            }
        }
    };

    const unsigned short* Wt = P.Wt;

    // L0: K=64 from global x; next = W1
    gemm(ic_t<2>{}, ic_t<4>{}, ic_t<4>{},
         [&](int mt, int kt) { return ldXg(mt, kt << 5, 63); },
         Wt + OFF_W0, 64, P.b[0], true, Wt + OFF_W1, 256, wave << 6);
    soft_barrier();

    // L1-3
    {
        const unsigned short* Wc[3] = {Wt + OFF_W1, Wt + OFF_W2, Wt + OFF_W3};
        const unsigned short* Wn[3] = {Wt + OFF_W2, Wt + OFF_W3, Wt + OFF_W4};
        const int Kpn[3] = {256, 256, 320};
        const float* bc[3] = {P.b[1], P.b[2], P.b[3]};
        for (int i = 0; i < 3; ++i) {
            gemm(ic_t<8>{}, ic_t<4>{}, ic_t<4>{},
                 [&](int mt, int kt) { return ldH(mt, kt); },
                 Wc[i], 256, bc[i], true, Wn[i], Kpn[i], wave << 6);
            soft_barrier();
        }
    }

    // L4: K=320 = [xyz(64) | h(256)]; next = W5
    gemm(ic_t<10>{}, ic_t<4>{}, ic_t<4>{},
         [&](int mt, int kt) { return (kt < 2) ? ldXg(mt, kt << 5, 63) : ldH(mt, kt - 2); },
         Wt + OFF_W4, 320, P.b[4], true, Wt + OFF_W5, 256, wave << 6);
    soft_barrier();

    // L5-7
    {
        const unsigned short* Wc[3] = {Wt + OFF_W5, Wt + OFF_W6, Wt + OFF_W7};
        const unsigned short* Wn[3] = {Wt + OFF_W6, Wt + OFF_W7, Wt + OFF_WF};
        const float* bc[3] = {P.b[5], P.b[6], P.b[7]};
        for (int i = 0; i < 3; ++i) {
            gemm(ic_t<8>{}, ic_t<4>{}, ic_t<4>{},
                 [&](int mt, int kt) { return ldH(mt, kt); },
                 Wc[i], 256, bc[i], true, Wn[i], 256, wave << 6);
            soft_barrier();
        }
    }
    // Hs = h (layer-7 out)

    // sigma = h @ ws + bs (reads h before WF's in-place overwrite: sigma's
    // ds_reads complete before WF's pre-epilogue barrier)
    float sig;
    {
        int rr = t >> 2, q = t & 3;
        float sp = 0.f;
#pragma unroll
        for (int j = 0; j < 8; ++j) {
            int cb = (q << 6) + (j << 3);
            bf16x8 h8 = *(const bf16x8*)(Hs + ((rr * 512 + (cb << 1)) ^ ((rr & 7) << 4)));
#pragma unroll
            for (int e = 0; e < 8; ++e) sp += (float)h8[e] * P.wsv[cb + e];
        }
        sp += __shfl_xor(sp, 1);
        sp += __shfl_xor(sp, 2);
        sig = sp + P.bsv[0];
    }

    // xyz_final = h @ wf + bf (no relu); next = WD (NT=2, Kp=288, cb=wave*32)
    gemm(ic_t<8>{}, ic_t<4>{}, ic_t<2>{},
         [&](int mt, int kt) { return ldH(mt, kt); },
         Wt + OFF_WF, 256, P.bfv, false, Wt + OFF_WD, 288, wave << 5);
    soft_barrier();

    // d = relu([xyz_final | dir] @ wd + bd): KT=9, NT=2 -> Hs cols 0..127;
    // dir (x cols 63..92) read from global (L2-hot)
    gemm(ic_t<9>{}, ic_t<2>{}, ic_t<0>{},
         [&](int mt, int kt) { return (kt < 8) ? ldH(mt, kt) : ldXg(mt, 63, 93); },
         Wt + OFF_WD, 288, P.bdv, true, nullptr, 0, 0);
    soft_barrier();

    // rgb = sigmoid(d @ wr + br); fused float4 store {r,g,b,sigma}
    {
        int rr = t >> 2, q = t & 3;
        float c0 = 0.f, c1 = 0.f, c2 = 0.f;
#pragma unroll
        for (int j = 0; j < 4; ++j) {
            int kb = (q << 5) + (j << 3);
            bf16x8 d8 = *(const bf16x8*)(Hs + ((rr * 512 + (kb << 1)) ^ ((rr & 7) << 4)));
#pragma unroll
            for (int e = 0; e < 8; ++e) {
                float dv = (float)d8[e];
                const float* w = P.wrv + (kb + e) * 3;
                c0 += dv * w[0]; c1 += dv * w[1]; c2 += dv * w[2];
            }
        }
        c0 += __shfl_xor(c0, 1); c0 += __shfl_xor(c0, 2);
        c1 += __shfl_xor(c1, 1); c1 += __shfl_xor(c1, 2);
        c2 += __shfl_xor(c2, 1); c2 += __shfl_xor(c2, 2);
        if (q == 0) {
            float4 o;
            o.x = 1.f / (1.f + __expf(-(c0 + P.brv[0])));
            o.y = 1.f / (1.f + __expf(-(c1 + P.brv[1])));
            o.z = 1.f / (1.f + __expf(-(c2 + P.brv[2])));
            o.w = sig;
            ((float4*)P.out)[blockRow + rr] = o;
        }
    }
}

extern "C" void kernel_launch(void* const* d_in, const int* in_sizes, int n_in,
                              void* d_out, int out_size, void* d_ws, size_t ws_size,
                              hipStream_t stream) {
    const float* x = (const float*)d_in[0];
    const float* w[8];
    const float* b[8];
    for (int i = 0; i < 8; ++i) {
        w[i] = (const float*)d_in[1 + 2 * i];
        b[i] = (const float*)d_in[2 + 2 * i];
    }
    const float* wf  = (const float*)d_in[17];
    const float* bfv = (const float*)d_in[18];
    const float* wd  = (const float*)d_in[19];
    const float* bdv = (const float*)d_in[20];
    const float* wsv = (const float*)d_in[21];
    const float* bsv = (const float*)d_in[22];
    const float* wrv = (const float*)d_in[23];
    const float* brv = (const float*)d_in[24];

    unsigned short* Wt = (unsigned short*)d_ws;

    prep_kernel<<<(W_TOTAL + 255) / 256, 256, 0, stream>>>(
        w[0], w[1], w[2], w[3], w[4], w[5], w[6], w[7], wf, wd, Wt);

    Params P;
    P.x = x; P.Wt = Wt;
    for (int i = 0; i < 8; ++i) P.b[i] = b[i];
    P.bfv = bfv; P.bdv = bdv; P.wsv = wsv; P.bsv = bsv; P.wrv = wrv; P.brv = brv;
    P.out = (float*)d_out;

    nerf_kernel<<<262144 / 64, 256, 0, stream>>>(P);
}

// Round 9
// 641.939 us; speedup vs baseline: 3.6823x; 3.6823x over previous
//
#include <hip/hip_runtime.h>

typedef __bf16  bf16x8 __attribute__((ext_vector_type(8)));
typedef float   f32x4  __attribute__((ext_vector_type(4)));
typedef unsigned int uint32x2 __attribute__((ext_vector_type(2)));

#define MFMA16(a,b,c) __builtin_amdgcn_mfma_f32_16x16x32_bf16((a),(b),(c),0,0,0)

template<int V> struct ic_t { static constexpr int value = V; };

// bf16 weight arena layout in d_ws (elements)
enum : int {
    OFF_W0 = 0,                      // [256][64]
    OFF_W1 = OFF_W0 + 256 * 64,      // [256][256]
    OFF_W2 = OFF_W1 + 256 * 256,
    OFF_W3 = OFF_W2 + 256 * 256,
    OFF_W4 = OFF_W3 + 256 * 256,     // [256][320]
    OFF_W5 = OFF_W4 + 256 * 320,
    OFF_W6 = OFF_W5 + 256 * 256,
    OFF_W7 = OFF_W6 + 256 * 256,
    OFF_WF = OFF_W7 + 256 * 256,     // [256][256]
    OFF_WD = OFF_WF + 256 * 256,     // [128][288]
    W_TOTAL = OFF_WD + 128 * 288
};

__device__ __forceinline__ unsigned short f2bf(float f) {
    unsigned int u = __float_as_uint(f);
    u += 0x7FFFu + ((u >> 16) & 1u);
    return (unsigned short)(u >> 16);
}

// Soft barrier: LDS ops visible + rendezvous, but global loads stay in flight.
__device__ __forceinline__ void soft_barrier() {
    asm volatile("s_waitcnt lgkmcnt(0)" ::: "memory");
    __builtin_amdgcn_s_barrier();
}

__device__ __forceinline__ void prep_one(const float* __restrict__ src,
                                         unsigned short* __restrict__ dst,
                                         int fout, int Kp, int n1, int n2, int n3,
                                         int idx) {
    int n = idx / Kp;
    int k = idx - n * Kp;
    float v = 0.f;
    if (k < n1)                 v = src[k * fout + n];
    else if (k >= n2 && k < n3) v = src[(k - (n2 - n1)) * fout + n];
    dst[n * Kp + k] = f2bf(v);
}

__global__ void prep_kernel(const float* w0, const float* w1, const float* w2,
                            const float* w3, const float* w4, const float* w5,
                            const float* w6, const float* w7, const float* wf,
                            const float* wd, unsigned short* dst) {
    int i = blockIdx.x * 256 + threadIdx.x;
    if (i < 256 * 64)  { prep_one(w0, dst + OFF_W0, 256,  64,  63,  64,  64, i); return; }
    i -= 256 * 64;
    if (i < 256 * 256) { prep_one(w1, dst + OFF_W1, 256, 256, 256, 256, 256, i); return; }
    i -= 256 * 256;
    if (i < 256 * 256) { prep_one(w2, dst + OFF_W2, 256, 256, 256, 256, 256, i); return; }
    i -= 256 * 256;
    if (i < 256 * 256) { prep_one(w3, dst + OFF_W3, 256, 256, 256, 256, 256, i); return; }
    i -= 256 * 256;
    if (i < 256 * 320) { prep_one(w4, dst + OFF_W4, 256, 320,  63,  64, 320, i); return; }
    i -= 256 * 320;
    if (i < 256 * 256) { prep_one(w5, dst + OFF_W5, 256, 256, 256, 256, 256, i); return; }
    i -= 256 * 256;
    if (i < 256 * 256) { prep_one(w6, dst + OFF_W6, 256, 256, 256, 256, 256, i); return; }
    i -= 256 * 256;
    if (i < 256 * 256) { prep_one(w7, dst + OFF_W7, 256, 256, 256, 256, 256, i); return; }
    i -= 256 * 256;
    if (i < 256 * 256) { prep_one(wf, dst + OFF_WF, 256, 256, 256, 256, 256, i); return; }
    i -= 256 * 256;
    if (i < 128 * 288) { prep_one(wd, dst + OFF_WD, 128, 288, 286, 288, 288, i); return; }
}

struct Params {
    const float* x;
    const unsigned short* Wt;
    const float* b[8];
    const float* bfv;
    const float* bdv;
    const float* wsv;
    const float* bsv;
    const float* wrv;
    const float* brv;
    float* out;
};

// 64 rows/block, 4 waves (256 thr), N-split 64 cols/wave (NT=4).
// SINGLE 32 KB Hs, in-place layers (pre-epilogue barrier); x read directly
// from global for L0/L4/dir. Swapped MFMA (D=[neuron][batch]); depth-2
// cross-layer B prefetch.
// __launch_bounds__(256,2): VGPR cap = 256/arg2 = 128 (empirical: arg2=4
// caps at 64 -> R8's 6.8 GB spill disaster). Actual VGPR ~116 <= 128 and
// LDS 32 KB let HW resident 4 blocks/CU = 16 waves/CU without the cap.
__global__ __launch_bounds__(256, 2) void nerf_kernel(Params P) {
    __shared__ char Hs[32768];   // [64][256] bf16, swz ^((row&7)<<4)

    const int t    = threadIdx.x;
    const int lane = t & 63;
    const int wave = t >> 6;          // 0..3
    const int lr   = lane & 15;
    const int lk   = lane >> 4;
    const int blockRow = blockIdx.x << 6;

    // ---- B pipeline (persistent across layers): bp0/bp1 = kt, kt+1 frags
    bf16x8 bp0[4], bp1[4];
    {   // preload layer-0 kt0/kt1
        const unsigned short* Wb0 = P.Wt + OFF_W0 + (size_t)((wave << 6) + lr) * 64 + (lk << 3);
#pragma unroll
        for (int nt = 0; nt < 4; ++nt) {
            bp0[nt] = *(const bf16x8*)(Wb0 + (size_t)(nt << 4) * 64);
            bp1[nt] = *(const bf16x8*)(Wb0 + (size_t)(nt << 4) * 64 + 32);
        }
    }

    // activation B-frag from GLOBAL x: batch row = blockRow+mt*16+lr,
    // k-elem j -> x col c0 + lk*8 + j, zero for c >= lim
    auto ldXg = [&](int mt, int c0, int lim) -> bf16x8 {
        const float* xr = P.x + (size_t)(blockRow + (mt << 4) + lr) * 93;
        bf16x8 r;
#pragma unroll
        for (int j = 0; j < 8; ++j) {
            int c = c0 + (lk << 3) + j;
            r[j] = (c < lim) ? (__bf16)xr[c] : (__bf16)0.f;
        }
        return r;
    };
    // activation B-frag from Hs: row = mt*16+lr, 16B contiguous k
    auto ldH = [&](int mt, int kt) -> bf16x8 {
        int row = (mt << 4) + lr;
        int off = (row * 512 + (kt << 6) + (lk << 4)) ^ ((row & 7) << 4);
        return *(const bf16x8*)(Hs + off);
    };

    // GEMM layer. KT=K/32, NT=N-tiles/wave, NTn = next layer's NT (0=none).
    // In-place: K-loop reads Hs -> soft barrier -> epilogue writes Hs.
    // Entry: bp0/bp1 = this layer's kt0/kt1. Exit: next layer's kt0/kt1.
    auto gemm = [&](auto KTt, auto NTt, auto NTnt, auto&& getA,
                    const unsigned short* W, int Kp, const float* bias, bool dorelu,
                    const unsigned short* Wn, int Kpn, int cbn) {
        constexpr int KT  = decltype(KTt)::value;
        constexpr int NT  = decltype(NTt)::value;
        constexpr int NTn = decltype(NTnt)::value;
        const int colbase = wave * (NT << 4);
        const unsigned short* Wb = W + (size_t)(colbase + lr) * Kp + (lk << 3);
        const unsigned short* Wbn = (NTn > 0) ? Wn + (size_t)(cbn + lr) * Kpn + (lk << 3) : nullptr;

        // bias folded into acc init (neuron = colbase + nt*16 + lk*4 + e)
        f32x4 acc[4][NT];
        {
            f32x4 bfr[NT];
#pragma unroll
            for (int nt = 0; nt < NT; ++nt)
                bfr[nt] = *(const f32x4*)(bias + colbase + (nt << 4) + (lk << 2));
#pragma unroll
            for (int mt = 0; mt < 4; ++mt)
#pragma unroll
                for (int nt = 0; nt < NT; ++nt) acc[mt][nt] = bfr[nt];
        }

        bf16x8 aC[4], aN[4];
#pragma unroll
        for (int mt = 0; mt < 4; ++mt) { aC[mt] = getA(mt, 0); aN[mt] = aC[mt]; }

#pragma unroll
        for (int kt = 0; kt < KT; ++kt) {
            // depth-2 B prefetch (wraps into next layer's kt0/kt1)
            bf16x8 bp2[NT];
            if (kt + 2 < KT) {
#pragma unroll
                for (int nt = 0; nt < NT; ++nt)
                    bp2[nt] = *(const bf16x8*)(Wb + (size_t)(nt << 4) * Kp + ((kt + 2) << 5));
            } else if (NTn > 0) {
#pragma unroll
                for (int nt = 0; nt < (NTn > 0 ? NTn : 1); ++nt)
                    bp2[nt] = *(const bf16x8*)(Wbn + (size_t)(nt << 4) * Kpn + ((kt + 2 - KT) << 5));
            } else {
#pragma unroll
                for (int nt = 0; nt < NT; ++nt) bp2[nt] = bp1[nt];
            }
            // A prefetch distance 1
            if (kt + 1 < KT) {
#pragma unroll
                for (int mt = 0; mt < 4; ++mt) aN[mt] = getA(mt, kt + 1);
            }
            __builtin_amdgcn_s_setprio(1);
#pragma unroll
            for (int nt = 0; nt < NT; ++nt) {
#pragma unroll
                for (int mt = 0; mt < 4; ++mt)
                    acc[mt][nt] = MFMA16(bp0[nt], aC[mt], acc[mt][nt]);  // D=[neuron][batch]
            }
            __builtin_amdgcn_s_setprio(0);
#pragma unroll
            for (int nt = 0; nt < 4; ++nt) { bp0[nt] = bp1[nt]; }
#pragma unroll
            for (int nt = 0; nt < NT; ++nt) { bp1[nt] = bp2[nt]; }
#pragma unroll
            for (int mt = 0; mt < 4; ++mt) aC[mt] = aN[mt];
        }

        // all waves done reading Hs before in-place overwrite
        soft_barrier();

        // epilogue: relu, pack 2x bf16 via cvt_pk, one b64 LDS write per tile
#pragma unroll
        for (int nt = 0; nt < NT; ++nt) {
#pragma unroll
            for (int mt = 0; mt < 4; ++mt) {
                f32x4 v = acc[mt][nt];
                if (dorelu) {
#pragma unroll
                    for (int e = 0; e < 4; ++e) v[e] = fmaxf(v[e], 0.f);
                }
                unsigned int lo, hi;
                asm("v_cvt_pk_bf16_f32 %0, %1, %2" : "=v"(lo) : "v"(v[0]), "v"(v[1]));
                asm("v_cvt_pk_bf16_f32 %0, %1, %2" : "=v"(hi) : "v"(v[2]), "v"(v[3]));
                int batch = (mt << 4) + lr;
                int off = (batch * 512 + ((colbase + (nt << 4) + (lk << 2)) << 1)) ^ ((batch & 7) << 4);
                uint32x2 w2 = {lo, hi};
                *(uint32x2*)(Hs + off) = w2;
            }
        }
    };

    const unsigned short* Wt = P.Wt;

    // L0: K=64 from global x; next = W1
    gemm(ic_t<2>{}, ic_t<4>{}, ic_t<4>{},
         [&](int mt, int kt) { return ldXg(mt, kt << 5, 63); },
         Wt + OFF_W0, 64, P.b[0], true, Wt + OFF_W1, 256, wave << 6);
    soft_barrier();

    // L1-3
    {
        const unsigned short* Wc[3] = {Wt + OFF_W1, Wt + OFF_W2, Wt + OFF_W3};
        const unsigned short* Wn[3] = {Wt + OFF_W2, Wt + OFF_W3, Wt + OFF_W4};
        const int Kpn[3] = {256, 256, 320};
        const float* bc[3] = {P.b[1], P.b[2], P.b[3]};
        for (int i = 0; i < 3; ++i) {
            gemm(ic_t<8>{}, ic_t<4>{}, ic_t<4>{},
                 [&](int mt, int kt) { return ldH(mt, kt); },
                 Wc[i], 256, bc[i], true, Wn[i], Kpn[i], wave << 6);
            soft_barrier();
        }
    }

    // L4: K=320 = [xyz(64) | h(256)]; next = W5
    gemm(ic_t<10>{}, ic_t<4>{}, ic_t<4>{},
         [&](int mt, int kt) { return (kt < 2) ? ldXg(mt, kt << 5, 63) : ldH(mt, kt - 2); },
         Wt + OFF_W4, 320, P.b[4], true, Wt + OFF_W5, 256, wave << 6);
    soft_barrier();

    // L5-7
    {
        const unsigned short* Wc[3] = {Wt + OFF_W5, Wt + OFF_W6, Wt + OFF_W7};
        const unsigned short* Wn[3] = {Wt + OFF_W6, Wt + OFF_W7, Wt + OFF_WF};
        const float* bc[3] = {P.b[5], P.b[6], P.b[7]};
        for (int i = 0; i < 3; ++i) {
            gemm(ic_t<8>{}, ic_t<4>{}, ic_t<4>{},
                 [&](int mt, int kt) { return ldH(mt, kt); },
                 Wc[i], 256, bc[i], true, Wn[i], 256, wave << 6);
            soft_barrier();
        }
    }
    // Hs = h (layer-7 out)

    // sigma = h @ ws + bs (reads h before WF's in-place overwrite; all waves'
    // sigma ds_reads complete before WF's pre-epilogue barrier)
    float sig;
    {
        int rr = t >> 2, q = t & 3;
        float sp = 0.f;
#pragma unroll
        for (int j = 0; j < 8; ++j) {
            int cb = (q << 6) + (j << 3);
            bf16x8 h8 = *(const bf16x8*)(Hs + ((rr * 512 + (cb << 1)) ^ ((rr & 7) << 4)));
#pragma unroll
            for (int e = 0; e < 8; ++e) sp += (float)h8[e] * P.wsv[cb + e];
        }
        sp += __shfl_xor(sp, 1);
        sp += __shfl_xor(sp, 2);
        sig = sp + P.bsv[0];
    }

    // xyz_final = h @ wf + bf (no relu); next = WD (NT=2, Kp=288, cb=wave*32)
    gemm(ic_t<8>{}, ic_t<4>{}, ic_t<2>{},
         [&](int mt, int kt) { return ldH(mt, kt); },
         Wt + OFF_WF, 256, P.bfv, false, Wt + OFF_WD, 288, wave << 5);
    soft_barrier();

    // d = relu([xyz_final | dir] @ wd + bd): KT=9, NT=2 -> Hs cols 0..127;
    // dir (x cols 63..92) read from global (L2-hot)
    gemm(ic_t<9>{}, ic_t<2>{}, ic_t<0>{},
         [&](int mt, int kt) { return (kt < 8) ? ldH(mt, kt) : ldXg(mt, 63, 93); },
         Wt + OFF_WD, 288, P.bdv, true, nullptr, 0, 0);
    soft_barrier();

    // rgb = sigmoid(d @ wr + br); fused float4 store {r,g,b,sigma}
    {
        int rr = t >> 2, q = t & 3;
        float c0 = 0.f, c1 = 0.f, c2 = 0.f;
#pragma unroll
        for (int j = 0; j < 4; ++j) {
            int kb = (q << 5) + (j << 3);
            bf16x8 d8 = *(const bf16x8*)(Hs + ((rr * 512 + (kb << 1)) ^ ((rr & 7) << 4)));
#pragma unroll
            for (int e = 0; e < 8; ++e) {
                float dv = (float)d8[e];
                const float* w = P.wrv + (kb + e) * 3;
                c0 += dv * w[0]; c1 += dv * w[1]; c2 += dv * w[2];
            }
        }
        c0 += __shfl_xor(c0, 1); c0 += __shfl_xor(c0, 2);
        c1 += __shfl_xor(c1, 1); c1 += __shfl_xor(c1, 2);
        c2 += __shfl_xor(c2, 1); c2 += __shfl_xor(c2, 2);
        if (q == 0) {
            float4 o;
            o.x = 1.f / (1.f + __expf(-(c0 + P.brv[0])));
            o.y = 1.f / (1.f + __expf(-(c1 + P.brv[1])));
            o.z = 1.f / (1.f + __expf(-(c2 + P.brv[2])));
            o.w = sig;
            ((float4*)P.out)[blockRow + rr] = o;
        }
    }
}

extern "C" void kernel_launch(void* const* d_in, const int* in_sizes, int n_in,
                              void* d_out, int out_size, void* d_ws, size_t ws_size,
                              hipStream_t stream) {
    const float* x = (const float*)d_in[0];
    const float* w[8];
    const float* b[8];
    for (int i = 0; i < 8; ++i) {
        w[i] = (const float*)d_in[1 + 2 * i];
        b[i] = (const float*)d_in[2 + 2 * i];
    }
    const float* wf  = (const float*)d_in[17];
    const float* bfv = (const float*)d_in[18];
    const float* wd  = (const float*)d_in[19];
    const float* bdv = (const float*)d_in[20];
    const float* wsv = (const float*)d_in[21];
    const float* bsv = (const float*)d_in[22];
    const float* wrv = (const float*)d_in[23];
    const float* brv = (const float*)d_in[24];

    unsigned short* Wt = (unsigned short*)d_ws;

    prep_kernel<<<(W_TOTAL + 255) / 256, 256, 0, stream>>>(
        w[0], w[1], w[2], w[3], w[4], w[5], w[6], w[7], wf, wd, Wt);

    Params P;
    P.x = x; P.Wt = Wt;
    for (int i = 0; i < 8; ++i) P.b[i] = b[i];
    P.bfv = bfv; P.bdv = bdv; P.wsv = wsv; P.bsv = bsv; P.wrv = wrv; P.brv = brv;
    P.out = (float*)d_out;

    nerf_kernel<<<262144 / 64, 256, 0, stream>>>(P);
}